// Round 13
// baseline (387.512 us; speedup 1.0000x reference)
//
#include <hip/hip_runtime.h>
#include <hip/hip_bf16.h>
#include <stdint.h>

// LSTM block: pre = [x|h_prev] @ [Wx|Rh]^T + bias; gates z,i,f,o; c = f*c_prev + i*z; h = o*tanh(c)
// GEMM M=16384 N=4096(n'=4h+g) K=2048 bf16 MFMA, fused epilogue.
// R13: 128x128 tile, 4 waves, 64KB LDS (4-slot K-half ring) -> 2 INDEPENDENT blocks/CU.
//      R4-era counted-vmcnt staging (VM4) + lockstep LGKM0 (SMEM-safe). Hypothesis: the
//      ~260us plateau is single-block barrier convoy; co-resident blocks fill the stalls.

typedef __attribute__((ext_vector_type(8))) short bf16x8;
typedef __attribute__((ext_vector_type(4))) float f32x4;
typedef __attribute__((ext_vector_type(8))) unsigned short u16x8;

#define AS1 __attribute__((address_space(1)))
#define AS3 __attribute__((address_space(3)))

constexpr int BATCH = 16384;
constexpr int HDIM  = 1024;
constexpr int KDIM  = 2048;
constexpr int NDIM  = 4096;

__device__ inline unsigned short f2bf(float f) {
  uint32_t u = __builtin_bit_cast(uint32_t, f);
  u += 0x7fffu + ((u >> 16) & 1u);
  return (unsigned short)(u >> 16);
}
__device__ inline u16x8 cvt8(const float* __restrict__ src) {
  float4 f0 = *(const float4*)src;
  float4 f1 = *(const float4*)(src + 4);
  u16x8 v;
  v[0] = f2bf(f0.x); v[1] = f2bf(f0.y); v[2] = f2bf(f0.z); v[3] = f2bf(f0.w);
  v[4] = f2bf(f1.x); v[5] = f2bf(f1.y); v[6] = f2bf(f1.z); v[7] = f2bf(f1.w);
  return v;
}
__device__ inline float sigmoid_f(float x) {
  float e = __builtin_amdgcn_exp2f(-1.4426950408889634f * x);
  return __builtin_amdgcn_rcpf(1.0f + e);
}
__device__ inline float tanh_f(float x) {
  float e = __builtin_amdgcn_exp2f(2.8853900817779268f * x);
  return 1.0f - 2.0f * __builtin_amdgcn_rcpf(1.0f + e);
}

// Fused pack: blocks [0,2048) -> XH; [2048,3072) -> Wp (first 16 also do bias).
__global__ void pack_all(const float* __restrict__ x, const float* __restrict__ hp,
                         const float* __restrict__ Wx, const float* __restrict__ Rh,
                         const float* __restrict__ bx, const float* __restrict__ bh,
                         unsigned short* __restrict__ xh, unsigned short* __restrict__ wp,
                         float* __restrict__ bias) {
  const int blk = blockIdx.x;
  if (blk < 2048) {
    const int64_t nch = (int64_t)BATCH * KDIM / 8;
    for (int64_t c = (int64_t)blk * blockDim.x + threadIdx.x; c < nch;
         c += (int64_t)2048 * blockDim.x) {
      const int b = (int)(c >> 8);
      const int k = ((int)c & 255) * 8;
      const float* src = (k < 1024) ? (x + (int64_t)b * 1024 + k)
                                    : (hp + (int64_t)b * 1024 + (k - 1024));
      *(u16x8*)(xh + c * 8) = cvt8(src);
    }
  } else {
    const int wblk = blk - 2048;
    if (wblk < 16) {
      const int n = wblk * 256 + threadIdx.x;   // 4096 total
      const int h = n >> 2, g = n & 3;
      bias[n] = bx[g * HDIM + h] + bh[g * HDIM + h];
    }
    const int64_t nch = (int64_t)NDIM * KDIM / 8;
    for (int64_t c = (int64_t)wblk * blockDim.x + threadIdx.x; c < nch;
         c += (int64_t)1024 * blockDim.x) {
      const int np = (int)(c >> 8);
      const int k = ((int)c & 255) * 8;
      const int h = np >> 2, g = np & 3;
      const float* src = (k < 1024) ? (Wx + (int64_t)(g * HDIM + h) * 1024 + k)
                                    : (Rh + (int64_t)(g * HDIM + h) * 1024 + (k - 1024));
      *(u16x8*)(wp + c * 8) = cvt8(src);
    }
  }
}

template <int OFF>
__device__ __forceinline__ bf16x8 dsb128(uint32_t a) {
  bf16x8 r;
  asm volatile("ds_read_b128 %0, %1 offset:%2" : "=v"(r) : "v"(a), "i"(OFF) : "memory");
  return r;
}

#define BARR    asm volatile("s_barrier" ::: "memory")
#define LGKM0   asm volatile("s_waitcnt lgkmcnt(0)" ::: "memory")
#define VM4     asm volatile("s_waitcnt vmcnt(4)" ::: "memory")
#define VM0     asm volatile("s_waitcnt vmcnt(0)" ::: "memory")
#define SCHED0  __builtin_amdgcn_sched_barrier(0)

// LDS (64KB): A K-half slots [4][128 rows][32 k] 8KB at slot*8192 (base 0);
// B same at 32768 + slot*8192. Row = 64B = 4 chunks of 16B; swizzle c' = c ^ ((row>>1)&3).
#define ISS(SLOT) { \
  fa[0] = dsb128<(SLOT)*8192>(av);        fa[1] = dsb128<(SLOT)*8192 + 1024>(av); \
  fa[2] = dsb128<(SLOT)*8192 + 2048>(av); fa[3] = dsb128<(SLOT)*8192 + 3072>(av); \
  fb[0] = dsb128<(SLOT)*8192>(bv);        fb[1] = dsb128<(SLOT)*8192 + 1024>(bv); \
  fb[2] = dsb128<(SLOT)*8192 + 2048>(bv); fb[3] = dsb128<(SLOT)*8192 + 3072>(bv); }

#define MFMA16 { \
  __builtin_amdgcn_s_setprio(1); \
  _Pragma("unroll") for (int mi = 0; mi < 4; ++mi) \
  _Pragma("unroll") for (int ni = 0; ni < 4; ++ni) \
    acc[mi][ni] = __builtin_amdgcn_mfma_f32_16x16x32_bf16(fa[mi], fb[ni], acc[mi][ni], 0, 0, 0); \
  __builtin_amdgcn_s_setprio(0); }

// Stage K-half JS into slot SLOT: 4 gloads (A rows 0-63, A rows 64-127, B same).
#define STAGE(JS, SLOT) { \
  __builtin_amdgcn_global_load_lds((const AS1 void*)(pA + (int64_t)(JS) * 64), \
      (AS3 void*)(smem_ + (SLOT)*8192 + dstOff), 16, 0, 0); \
  __builtin_amdgcn_global_load_lds((const AS1 void*)(pA + 262144 + (int64_t)(JS) * 64), \
      (AS3 void*)(smem_ + (SLOT)*8192 + 4096 + dstOff), 16, 0, 0); \
  __builtin_amdgcn_global_load_lds((const AS1 void*)(pB + (int64_t)(JS) * 64), \
      (AS3 void*)(smem_ + 32768 + (SLOT)*8192 + dstOff), 16, 0, 0); \
  __builtin_amdgcn_global_load_lds((const AS1 void*)(pB + 262144 + (int64_t)(JS) * 64), \
      (AS3 void*)(smem_ + 32768 + (SLOT)*8192 + 4096 + dstOff), 16, 0, 0); }

// Phase for K-half j = 4*it + P: stage j+2 (lead-2), read slot j&3, lockstep LGKM0,
// 16 MFMA, VM4 (drains stage j+1 -> landed for ISS at j+1), barrier.
#define PHASE(P) { \
  int js = 4 * it + (P) + 2; if (js > 63) js = 63; \
  STAGE(js, ((P) + 2) & 3) \
  ISS(P) \
  LGKM0; SCHED0; MFMA16 VM4; BARR; }

__global__ __launch_bounds__(256, 4) void lstm_gemm(
    const unsigned short* __restrict__ XH, const unsigned short* __restrict__ Wp,
    const float* __restrict__ bias, const float* __restrict__ c_prev,
    float* __restrict__ out_h, float* __restrict__ out_c) {
  __shared__ __align__(1024) char smem_[65536];

  const int tid  = threadIdx.x;
  const int l    = tid & 63;
  const int w    = tid >> 6;          // 4 waves: 2M x 2N
  const int wr   = w >> 1, wc = w & 1;
  const int la   = l & 15;
  const int kg   = l >> 4;

  // XCD swizzle: xcd owns 4 tile_n columns (B-panels 4 x 512KB, L2-resident), tm-major.
  const int xcd = blockIdx.x & 7;
  const int q   = blockIdx.x >> 3;          // [0,512)
  const int tn  = xcd * 4 + (q & 3);
  const int tm  = q >> 2;                   // [0,128)
  const int m0  = tm * 128;
  const int n0  = tn * 128;

  // Staging: thread t stages chunk t (row t>>2, chunk t&3) and chunk 256+t (row 64+(t>>2)).
  // Source chunk pre-swizzled: (t&3) ^ ((t>>3)&3)  [(row>>1)&3 == (t>>3)&3, +64 invariant].
  const int rbase = tid >> 2;
  const int ck    = (tid & 3) ^ ((tid >> 3) & 3);
  const char* pA = (const char*)XH + (int64_t)(m0 + rbase) * 4096 + ck * 16;
  const char* pB = (const char*)Wp + (int64_t)(n0 + rbase) * 4096 + ck * 16;
  const int dstOff = w * 1024;              // + lane*16 by HW -> byte = tid*16 (linear)

  // Fragment reads: A row = wr*64 + mi*16 + la, B row = wc*64 + ni*16 + la;
  // chunk = kg ^ ((la>>1)&3) (mi*16 ≡ 0 mod 8 -> la-only swizzle).
  const int cc = kg ^ ((la >> 1) & 3);
  const uint32_t lds0 = (uint32_t)(uintptr_t)(AS3 char*)smem_;
  const uint32_t av = lds0 + wr * 4096 + la * 64 + cc * 16;
  const uint32_t bv = lds0 + 32768 + wc * 4096 + la * 64 + cc * 16;

  f32x4 acc[4][4] = {};
  bf16x8 fa[4], fb[4];

  // Prologue: stage K-halves 0,1 (8 gloads); VM4 drains k0 (k1 in flight); barrier.
  STAGE(0, 0)
  STAGE(1, 1)
  VM4; BARR;

#pragma unroll 1
  for (int it = 0; it < 16; ++it) {
    PHASE(0)
    PHASE(1)
    PHASE(2)
    PHASE(3)
  }

  // ---- fused LSTM epilogue (drain clamped stages, then reuse LDS; wave-private) ----
  VM0;
  __syncthreads();
  float* ew = (float*)smem_ + w * 1088;     // 16 x 68 floats per wave (17.4KB total)
  const float4 bias4 = *(const float4*)(bias + n0 + wc * 64 + 4 * la);
  const int hg = ((n0 + wc * 64) >> 2) + la;

#pragma unroll
  for (int mi = 0; mi < 4; ++mi) {
#pragma unroll
    for (int ni = 0; ni < 4; ++ni)
#pragma unroll
      for (int r = 0; r < 4; ++r)
        ew[(4 * kg + r) * 68 + ni * 16 + la] = acc[mi][ni][r];
#pragma unroll
    for (int p = 0; p < 4; ++p) {
      const int row = p * 4 + kg;
      float4 g4 = *(const float4*)(ew + row * 68 + 4 * la);   // z,i,f,o for one (b,h)
      const int b = m0 + wr * 64 + mi * 16 + row;
      const uint32_t oidx = (uint32_t)b * HDIM + (uint32_t)hg;
      const float cp = c_prev[oidx];
      const float zg = tanh_f(g4.x + bias4.x);
      const float ig = sigmoid_f(g4.y + bias4.y);
      const float fg = sigmoid_f(g4.z + bias4.z);
      const float og = sigmoid_f(g4.w + bias4.w);
      const float cn = fg * cp + ig * zg;
      out_h[oidx] = og * tanh_f(cn);
      out_c[oidx] = cn;
    }
  }
}

extern "C" void kernel_launch(void* const* d_in, const int* in_sizes, int n_in,
                              void* d_out, int out_size, void* d_ws, size_t ws_size,
                              hipStream_t stream) {
  const float* x  = (const float*)d_in[0];
  const float* hp = (const float*)d_in[1];
  const float* cp = (const float*)d_in[2];
  const float* Wx = (const float*)d_in[3];
  const float* bx = (const float*)d_in[4];
  const float* Rh = (const float*)d_in[5];
  const float* bh = (const float*)d_in[6];

  unsigned short* XH = (unsigned short*)d_ws;                 // 64 MB
  unsigned short* Wp = XH + (size_t)BATCH * KDIM;             // 16 MB
  float* bias = (float*)(Wp + (size_t)NDIM * KDIM);           // 16 KB
  float* out_h = (float*)d_out;
  float* out_c = out_h + (size_t)BATCH * HDIM;

  pack_all<<<3072, 256, 0, stream>>>(x, hp, Wx, Rh, bx, bh, XH, Wp, bias);
  lstm_gemm<<<4096, 256, 0, stream>>>(XH, Wp, bias, cp, out_h, out_c);
}

// Round 14
// 303.303 us; speedup vs baseline: 1.2776x; 1.2776x over previous
//
#include <hip/hip_runtime.h>
#include <hip/hip_bf16.h>
#include <stdint.h>

// LSTM block: pre = [x|h_prev] @ [Wx|Rh]^T + bias; gates z,i,f,o; c = f*c_prev + i*z; h = o*tanh(c)
// GEMM M=16384 N=4096(n'=4h+g) K=2048 bf16 MFMA, fused epilogue.
// R14: R12 (8-wave 256² tile, counted-lgkm read-ahead, VM6) + SECOND barrier per phase
//      (m201's {reads+stage | BARR | wait+MFMA | BARR} alignment). Single-variable A/B vs R12.

typedef __attribute__((ext_vector_type(8))) short bf16x8;
typedef __attribute__((ext_vector_type(4))) float f32x4;
typedef __attribute__((ext_vector_type(8))) unsigned short u16x8;

#define AS1 __attribute__((address_space(1)))
#define AS3 __attribute__((address_space(3)))

constexpr int BATCH = 16384;
constexpr int HDIM  = 1024;
constexpr int KDIM  = 2048;
constexpr int NDIM  = 4096;

__device__ inline unsigned short f2bf(float f) {
  uint32_t u = __builtin_bit_cast(uint32_t, f);
  u += 0x7fffu + ((u >> 16) & 1u);
  return (unsigned short)(u >> 16);
}
__device__ inline u16x8 cvt8(const float* __restrict__ src) {
  float4 f0 = *(const float4*)src;
  float4 f1 = *(const float4*)(src + 4);
  u16x8 v;
  v[0] = f2bf(f0.x); v[1] = f2bf(f0.y); v[2] = f2bf(f0.z); v[3] = f2bf(f0.w);
  v[4] = f2bf(f1.x); v[5] = f2bf(f1.y); v[6] = f2bf(f1.z); v[7] = f2bf(f1.w);
  return v;
}
__device__ inline float sigmoid_f(float x) {
  float e = __builtin_amdgcn_exp2f(-1.4426950408889634f * x);
  return __builtin_amdgcn_rcpf(1.0f + e);
}
__device__ inline float tanh_f(float x) {
  float e = __builtin_amdgcn_exp2f(2.8853900817779268f * x);
  return 1.0f - 2.0f * __builtin_amdgcn_rcpf(1.0f + e);
}

// Fused pack: blocks [0,2048) -> XH; [2048,3072) -> Wp (first 16 also do bias).
__global__ void pack_all(const float* __restrict__ x, const float* __restrict__ hp,
                         const float* __restrict__ Wx, const float* __restrict__ Rh,
                         const float* __restrict__ bx, const float* __restrict__ bh,
                         unsigned short* __restrict__ xh, unsigned short* __restrict__ wp,
                         float* __restrict__ bias) {
  const int blk = blockIdx.x;
  if (blk < 2048) {
    const int64_t nch = (int64_t)BATCH * KDIM / 8;
    for (int64_t c = (int64_t)blk * blockDim.x + threadIdx.x; c < nch;
         c += (int64_t)2048 * blockDim.x) {
      const int b = (int)(c >> 8);
      const int k = ((int)c & 255) * 8;
      const float* src = (k < 1024) ? (x + (int64_t)b * 1024 + k)
                                    : (hp + (int64_t)b * 1024 + (k - 1024));
      *(u16x8*)(xh + c * 8) = cvt8(src);
    }
  } else {
    const int wblk = blk - 2048;
    if (wblk < 16) {
      const int n = wblk * 256 + threadIdx.x;   // 4096 total
      const int h = n >> 2, g = n & 3;
      bias[n] = bx[g * HDIM + h] + bh[g * HDIM + h];
    }
    const int64_t nch = (int64_t)NDIM * KDIM / 8;
    for (int64_t c = (int64_t)wblk * blockDim.x + threadIdx.x; c < nch;
         c += (int64_t)1024 * blockDim.x) {
      const int np = (int)(c >> 8);
      const int k = ((int)c & 255) * 8;
      const int h = np >> 2, g = np & 3;
      const float* src = (k < 1024) ? (Wx + (int64_t)(g * HDIM + h) * 1024 + k)
                                    : (Rh + (int64_t)(g * HDIM + h) * 1024 + (k - 1024));
      *(u16x8*)(wp + c * 8) = cvt8(src);
    }
  }
}

template <int OFF>
__device__ __forceinline__ bf16x8 dsb128(uint32_t a) {
  bf16x8 r;
  asm volatile("ds_read_b128 %0, %1 offset:%2" : "=v"(r) : "v"(a), "i"(OFF) : "memory");
  return r;
}

#define BARR   asm volatile("s_barrier" ::: "memory")
#define LGKM4  asm volatile("s_waitcnt lgkmcnt(4)" ::: "memory")
#define LGKM8  asm volatile("s_waitcnt lgkmcnt(8)" ::: "memory")
#define VM6    asm volatile("s_waitcnt vmcnt(6)" ::: "memory")
#define VM0    asm volatile("s_waitcnt vmcnt(0)" ::: "memory")
#define SCHED0 __builtin_amdgcn_sched_barrier(0)

// LDS map (bytes): A halves 16KB at buf*32768+kh*16384 (A base 0, B base 65536).
// Half layout: [256 rows][4 chunks of 16B], chunk swizzle c' = c ^ ((row>>1)&3).
#define ISS_A(FA, BUF, KH, MH) { constexpr int _o = (BUF)*32768 + (KH)*16384 + (MH)*4096; \
  FA[0] = dsb128<_o>(av); FA[1] = dsb128<_o+1024>(av);                                     \
  FA[2] = dsb128<_o+2048>(av); FA[3] = dsb128<_o+3072>(av); }
#define ISS_B(FB, BUF, KH) { constexpr int _o = (BUF)*32768 + (KH)*16384; \
  FB[0] = dsb128<_o>(bv); FB[1] = dsb128<_o+1024>(bv);                     \
  FB[2] = dsb128<_o+2048>(bv); FB[3] = dsb128<_o+3072>(bv); }

#define MFMA16(FA, FB, MB) { \
  __builtin_amdgcn_s_setprio(1); \
  _Pragma("unroll") for (int j = 0; j < 4; ++j) \
  _Pragma("unroll") for (int ni = 0; ni < 4; ++ni) \
    acc[(MB)*4 + j][ni] = __builtin_amdgcn_mfma_f32_16x16x32_bf16(FA[j], FB[ni], acc[(MB)*4 + j][ni], 0, 0, 0); \
  __builtin_amdgcn_s_setprio(0); }

#define STAGE(SRC, DOFF) { \
  __builtin_amdgcn_global_load_lds((const AS1 void*)(SRC), (AS3 void*)(dstL + (DOFF)), 16, 0, 0); \
  __builtin_amdgcn_global_load_lds((const AS1 void*)((SRC) + 524288), (AS3 void*)(dstL + (DOFF) + 8192), 16, 0, 0); }

__global__ __launch_bounds__(512, 2) void lstm_gemm(
    const unsigned short* __restrict__ XH, const unsigned short* __restrict__ Wp,
    const float* __restrict__ bias, const float* __restrict__ c_prev,
    float* __restrict__ out_h, float* __restrict__ out_c) {
  __shared__ __align__(1024) char smem_[131072];

  const int tid  = threadIdx.x;
  const int l    = tid & 63;
  const int w    = tid >> 6;          // 8 waves: 2M x 4N
  const int wr   = w >> 2, wc = w & 3;
  const int la   = l & 15;
  const int kg   = l >> 4;

  // XCD swizzle: xcd owns tn pair (B-panel 2 x 1MB L2-resident), tm-major within.
  const int xcd = blockIdx.x & 7;
  const int q   = blockIdx.x >> 3;
  const int tn  = xcd * 2 + (q & 1);
  const int tm  = q >> 1;
  const int m0  = tm * 256;
  const int n0  = tn * 256;

  // Staging: lane l of wave w, load i: row = w*16 + (l>>2) + i*128, chunk c = l&3,
  // source k-chunk = c ^ ((row>>1)&3) = (l&3) ^ ((l>>3)&3). LDS dest linear.
  const int rbase = w * 16 + (l >> 2);
  const int ck    = (l & 3) ^ ((l >> 3) & 3);
  const char* pA = (const char*)XH + (int64_t)(m0 + rbase) * 4096 + ck * 16;
  const char* pB = (const char*)Wp + (int64_t)(n0 + rbase) * 4096 + ck * 16;
  char* dstL = smem_ + w * 1024;

  // Fragment read addresses: row*64 + (kg ^ ((la>>1)&3))*16
  const int cc = kg ^ ((la >> 1) & 3);
  const uint32_t lds0 = (uint32_t)(uintptr_t)(AS3 char*)smem_;
  const uint32_t av = lds0 + wr * 8192 + la * 64 + cc * 16;
  const uint32_t bv = lds0 + 65536 + wc * 4096 + la * 64 + cc * 16;

  f32x4 acc[8][4] = {};
  bf16x8 fa0[4], fa1[4], fb0[4], fb1[4];

  // Prologue: stage t0 (4 halves) + t1 {B.kh0, A.kh0, B.kh1}; gate t0; issue ph0 reads.
  STAGE(pB,       65536);   // t0.B.kh0
  STAGE(pA,       0);       // t0.A.kh0
  STAGE(pB + 64,  81920);   // t0.B.kh1
  STAGE(pA + 64,  16384);   // t0.A.kh1
  STAGE(pB + 128, 98304);   // t1.B.kh0
  STAGE(pA + 128, 32768);   // t1.A.kh0
  STAGE(pB + 192, 114688);  // t1.B.kh1
  VM6; BARR;
  ISS_B(fb0, 0, 0) ISS_A(fa0, 0, 0, 0)

#pragma unroll 1
  for (int it = 0; it < 16; ++it) {
    int kt2 = 2 * it + 2; if (kt2 > 31) kt2 = 31;
    int kt3 = 2 * it + 3; if (kt3 > 31) kt3 = 31;
    const char* sA1 = pA + (2 * it + 1) * 128;
    const char* sA2 = pA + kt2 * 128;
    const char* sA3 = pA + kt3 * 128;
    const char* sB2 = pB + kt2 * 128;
    const char* sB3 = pB + kt3 * 128;

    // ph0: consume (fa0,fb0)=t.kh0.mh0; issue fa1 <- t.kh0.mh1
    BARR;
    STAGE(sA1 + 64, 49152);          // t+1.A.kh1 (dead since prev ph7 consume)
    ISS_A(fa1, 0, 0, 1)
    LGKM4; SCHED0; MFMA16(fa0, fb0, 0)
    BARR;                            // m201-style post-MFMA phase alignment
    // ph1: consume (fa1,fb0); issue (fb1,fa0) <- t.kh1
    BARR;
    STAGE(sB2, 65536);               // t+2.B.kh0
    ISS_B(fb1, 0, 1) ISS_A(fa0, 0, 1, 0)
    LGKM8; SCHED0; MFMA16(fa1, fb0, 1)
    VM6;
    BARR;
    // ph2: consume (fa0,fb1); issue fa1 <- t.kh1.mh1
    BARR;
    STAGE(sA2, 0);                   // t+2.A.kh0
    ISS_A(fa1, 0, 1, 1)
    LGKM4; SCHED0; MFMA16(fa0, fb1, 0)
    BARR;
    // ph3: consume (fa1,fb1); issue (fb0,fa0) <- t+1.kh0
    BARR;
    STAGE(sB2 + 64, 81920);          // t+2.B.kh1
    ISS_B(fb0, 1, 0) ISS_A(fa0, 1, 0, 0)
    LGKM8; SCHED0; MFMA16(fa1, fb1, 1)
    VM6;
    BARR;
    // ph4: consume (fa0,fb0); issue fa1 <- t+1.kh0.mh1
    BARR;
    STAGE(sA2 + 64, 16384);          // t+2.A.kh1
    ISS_A(fa1, 1, 0, 1)
    LGKM4; SCHED0; MFMA16(fa0, fb0, 0)
    BARR;
    // ph5: consume (fa1,fb0); issue (fb1,fa0) <- t+1.kh1
    BARR;
    STAGE(sB3, 98304);               // t+3.B.kh0
    ISS_B(fb1, 1, 1) ISS_A(fa0, 1, 1, 0)
    LGKM8; SCHED0; MFMA16(fa1, fb0, 1)
    VM6;
    BARR;
    // ph6: consume (fa0,fb1); issue fa1 <- t+1.kh1.mh1
    BARR;
    STAGE(sA3, 32768);               // t+3.A.kh0
    ISS_A(fa1, 1, 1, 1)
    LGKM4; SCHED0; MFMA16(fa0, fb1, 0)
    BARR;
    // ph7: consume (fa1,fb1); issue (fb0,fa0) <- next-iter t.kh0
    BARR;
    STAGE(sB3 + 64, 114688);         // t+3.B.kh1
    ISS_B(fb0, 0, 0) ISS_A(fa0, 0, 0, 0)
    LGKM8; SCHED0; MFMA16(fa1, fb1, 1)
    VM6;
    BARR;
  }

  // ---- fused LSTM epilogue (drain, then reuse LDS; wave-private) ----
  VM0;
  __syncthreads();
  float* ew = (float*)smem_ + w * 1088;     // 16 x 68 floats per wave
  const float4 bias4 = *(const float4*)(bias + n0 + wc * 64 + 4 * la);
  const int hg = ((n0 + wc * 64) >> 2) + la;

#pragma unroll
  for (int mi = 0; mi < 8; ++mi) {
#pragma unroll
    for (int ni = 0; ni < 4; ++ni)
#pragma unroll
      for (int r = 0; r < 4; ++r)
        ew[(4 * kg + r) * 68 + ni * 16 + la] = acc[mi][ni][r];
#pragma unroll
    for (int p = 0; p < 4; ++p) {
      const int row = p * 4 + kg;
      float4 g4 = *(const float4*)(ew + row * 68 + 4 * la);   // z,i,f,o for one (b,h)
      const int b = m0 + wr * 128 + mi * 16 + row;
      const uint32_t oidx = (uint32_t)b * HDIM + (uint32_t)hg;
      const float cp = c_prev[oidx];
      const float zg = tanh_f(g4.x + bias4.x);
      const float ig = sigmoid_f(g4.y + bias4.y);
      const float fg = sigmoid_f(g4.z + bias4.z);
      const float og = sigmoid_f(g4.w + bias4.w);
      const float cn = fg * cp + ig * zg;
      out_h[oidx] = og * tanh_f(cn);
      out_c[oidx] = cn;
    }
  }
}

extern "C" void kernel_launch(void* const* d_in, const int* in_sizes, int n_in,
                              void* d_out, int out_size, void* d_ws, size_t ws_size,
                              hipStream_t stream) {
  const float* x  = (const float*)d_in[0];
  const float* hp = (const float*)d_in[1];
  const float* cp = (const float*)d_in[2];
  const float* Wx = (const float*)d_in[3];
  const float* bx = (const float*)d_in[4];
  const float* Rh = (const float*)d_in[5];
  const float* bh = (const float*)d_in[6];

  unsigned short* XH = (unsigned short*)d_ws;                 // 64 MB
  unsigned short* Wp = XH + (size_t)BATCH * KDIM;             // 16 MB
  float* bias = (float*)(Wp + (size_t)NDIM * KDIM);           // 16 KB
  float* out_h = (float*)d_out;
  float* out_c = out_h + (size_t)BATCH * HDIM;

  pack_all<<<3072, 256, 0, stream>>>(x, hp, Wx, Rh, bx, bh, XH, Wp, bias);
  lstm_gemm<<<1024, 512, 0, stream>>>(XH, Wp, bias, cp, out_h, out_c);
}

// Round 15
// 299.259 us; speedup vs baseline: 1.2949x; 1.0135x over previous
//
#include <hip/hip_runtime.h>
#include <hip/hip_bf16.h>
#include <stdint.h>

// LSTM block: pre = [x|h_prev] @ [Wx|Rh]^T + bias; gates z,i,f,o; c = f*c_prev + i*z; h = o*tanh(c)
// GEMM M=16384 N=4096(n'=4h+g) K=2048 bf16 MFMA, fused epilogue.
// R15 (final config): R12's GEMM (8-wave 256² tile, counted-lgkm read-ahead, VM6, single
//      barrier/phase — best measured: 260.2us, 1054 TF) + epilogue c_prev register
//      prefetch (hides ~500cyc L3/HBM latency under the LDS transpose).

typedef __attribute__((ext_vector_type(8))) short bf16x8;
typedef __attribute__((ext_vector_type(4))) float f32x4;
typedef __attribute__((ext_vector_type(8))) unsigned short u16x8;

#define AS1 __attribute__((address_space(1)))
#define AS3 __attribute__((address_space(3)))

constexpr int BATCH = 16384;
constexpr int HDIM  = 1024;
constexpr int KDIM  = 2048;
constexpr int NDIM  = 4096;

__device__ inline unsigned short f2bf(float f) {
  uint32_t u = __builtin_bit_cast(uint32_t, f);
  u += 0x7fffu + ((u >> 16) & 1u);
  return (unsigned short)(u >> 16);
}
__device__ inline u16x8 cvt8(const float* __restrict__ src) {
  float4 f0 = *(const float4*)src;
  float4 f1 = *(const float4*)(src + 4);
  u16x8 v;
  v[0] = f2bf(f0.x); v[1] = f2bf(f0.y); v[2] = f2bf(f0.z); v[3] = f2bf(f0.w);
  v[4] = f2bf(f1.x); v[5] = f2bf(f1.y); v[6] = f2bf(f1.z); v[7] = f2bf(f1.w);
  return v;
}
__device__ inline float sigmoid_f(float x) {
  float e = __builtin_amdgcn_exp2f(-1.4426950408889634f * x);
  return __builtin_amdgcn_rcpf(1.0f + e);
}
__device__ inline float tanh_f(float x) {
  float e = __builtin_amdgcn_exp2f(2.8853900817779268f * x);
  return 1.0f - 2.0f * __builtin_amdgcn_rcpf(1.0f + e);
}

// Fused pack: blocks [0,2048) -> XH; [2048,3072) -> Wp (first 16 also do bias).
__global__ void pack_all(const float* __restrict__ x, const float* __restrict__ hp,
                         const float* __restrict__ Wx, const float* __restrict__ Rh,
                         const float* __restrict__ bx, const float* __restrict__ bh,
                         unsigned short* __restrict__ xh, unsigned short* __restrict__ wp,
                         float* __restrict__ bias) {
  const int blk = blockIdx.x;
  if (blk < 2048) {
    const int64_t nch = (int64_t)BATCH * KDIM / 8;
    for (int64_t c = (int64_t)blk * blockDim.x + threadIdx.x; c < nch;
         c += (int64_t)2048 * blockDim.x) {
      const int b = (int)(c >> 8);
      const int k = ((int)c & 255) * 8;
      const float* src = (k < 1024) ? (x + (int64_t)b * 1024 + k)
                                    : (hp + (int64_t)b * 1024 + (k - 1024));
      *(u16x8*)(xh + c * 8) = cvt8(src);
    }
  } else {
    const int wblk = blk - 2048;
    if (wblk < 16) {
      const int n = wblk * 256 + threadIdx.x;   // 4096 total
      const int h = n >> 2, g = n & 3;
      bias[n] = bx[g * HDIM + h] + bh[g * HDIM + h];
    }
    const int64_t nch = (int64_t)NDIM * KDIM / 8;
    for (int64_t c = (int64_t)wblk * blockDim.x + threadIdx.x; c < nch;
         c += (int64_t)1024 * blockDim.x) {
      const int np = (int)(c >> 8);
      const int k = ((int)c & 255) * 8;
      const int h = np >> 2, g = np & 3;
      const float* src = (k < 1024) ? (Wx + (int64_t)(g * HDIM + h) * 1024 + k)
                                    : (Rh + (int64_t)(g * HDIM + h) * 1024 + (k - 1024));
      *(u16x8*)(wp + c * 8) = cvt8(src);
    }
  }
}

template <int OFF>
__device__ __forceinline__ bf16x8 dsb128(uint32_t a) {
  bf16x8 r;
  asm volatile("ds_read_b128 %0, %1 offset:%2" : "=v"(r) : "v"(a), "i"(OFF) : "memory");
  return r;
}

#define BARR   asm volatile("s_barrier" ::: "memory")
#define LGKM4  asm volatile("s_waitcnt lgkmcnt(4)" ::: "memory")
#define LGKM8  asm volatile("s_waitcnt lgkmcnt(8)" ::: "memory")
#define VM6    asm volatile("s_waitcnt vmcnt(6)" ::: "memory")
#define VM0    asm volatile("s_waitcnt vmcnt(0)" ::: "memory")
#define SCHED0 __builtin_amdgcn_sched_barrier(0)

// LDS map (bytes): A halves 16KB at buf*32768+kh*16384 (A base 0, B base 65536).
// Half layout: [256 rows][4 chunks of 16B], chunk swizzle c' = c ^ ((row>>1)&3).
#define ISS_A(FA, BUF, KH, MH) { constexpr int _o = (BUF)*32768 + (KH)*16384 + (MH)*4096; \
  FA[0] = dsb128<_o>(av); FA[1] = dsb128<_o+1024>(av);                                     \
  FA[2] = dsb128<_o+2048>(av); FA[3] = dsb128<_o+3072>(av); }
#define ISS_B(FB, BUF, KH) { constexpr int _o = (BUF)*32768 + (KH)*16384; \
  FB[0] = dsb128<_o>(bv); FB[1] = dsb128<_o+1024>(bv);                     \
  FB[2] = dsb128<_o+2048>(bv); FB[3] = dsb128<_o+3072>(bv); }

#define MFMA16(FA, FB, MB) { \
  __builtin_amdgcn_s_setprio(1); \
  _Pragma("unroll") for (int j = 0; j < 4; ++j) \
  _Pragma("unroll") for (int ni = 0; ni < 4; ++ni) \
    acc[(MB)*4 + j][ni] = __builtin_amdgcn_mfma_f32_16x16x32_bf16(FA[j], FB[ni], acc[(MB)*4 + j][ni], 0, 0, 0); \
  __builtin_amdgcn_s_setprio(0); }

#define STAGE(SRC, DOFF) { \
  __builtin_amdgcn_global_load_lds((const AS1 void*)(SRC), (AS3 void*)(dstL + (DOFF)), 16, 0, 0); \
  __builtin_amdgcn_global_load_lds((const AS1 void*)((SRC) + 524288), (AS3 void*)(dstL + (DOFF) + 8192), 16, 0, 0); }

__global__ __launch_bounds__(512, 2) void lstm_gemm(
    const unsigned short* __restrict__ XH, const unsigned short* __restrict__ Wp,
    const float* __restrict__ bias, const float* __restrict__ c_prev,
    float* __restrict__ out_h, float* __restrict__ out_c) {
  __shared__ __align__(1024) char smem_[131072];

  const int tid  = threadIdx.x;
  const int l    = tid & 63;
  const int w    = tid >> 6;          // 8 waves: 2M x 4N
  const int wr   = w >> 2, wc = w & 3;
  const int la   = l & 15;
  const int kg   = l >> 4;

  // XCD swizzle: xcd owns tn pair (B-panel 2 x 1MB L2-resident), tm-major within.
  const int xcd = blockIdx.x & 7;
  const int q   = blockIdx.x >> 3;
  const int tn  = xcd * 2 + (q & 1);
  const int tm  = q >> 1;
  const int m0  = tm * 256;
  const int n0  = tn * 256;

  // Staging: lane l of wave w, load i: row = w*16 + (l>>2) + i*128, chunk c = l&3,
  // source k-chunk = c ^ ((row>>1)&3) = (l&3) ^ ((l>>3)&3). LDS dest linear.
  const int rbase = w * 16 + (l >> 2);
  const int ck    = (l & 3) ^ ((l >> 3) & 3);
  const char* pA = (const char*)XH + (int64_t)(m0 + rbase) * 4096 + ck * 16;
  const char* pB = (const char*)Wp + (int64_t)(n0 + rbase) * 4096 + ck * 16;
  char* dstL = smem_ + w * 1024;

  // Fragment read addresses: row*64 + (kg ^ ((la>>1)&3))*16
  const int cc = kg ^ ((la >> 1) & 3);
  const uint32_t lds0 = (uint32_t)(uintptr_t)(AS3 char*)smem_;
  const uint32_t av = lds0 + wr * 8192 + la * 64 + cc * 16;
  const uint32_t bv = lds0 + 65536 + wc * 4096 + la * 64 + cc * 16;

  f32x4 acc[8][4] = {};
  bf16x8 fa0[4], fa1[4], fb0[4], fb1[4];

  // Prologue: stage t0 (4 halves) + t1 {B.kh0, A.kh0, B.kh1}; gate t0; issue ph0 reads.
  STAGE(pB,       65536);   // t0.B.kh0
  STAGE(pA,       0);       // t0.A.kh0
  STAGE(pB + 64,  81920);   // t0.B.kh1
  STAGE(pA + 64,  16384);   // t0.A.kh1
  STAGE(pB + 128, 98304);   // t1.B.kh0
  STAGE(pA + 128, 32768);   // t1.A.kh0
  STAGE(pB + 192, 114688);  // t1.B.kh1
  VM6; BARR;
  ISS_B(fb0, 0, 0) ISS_A(fa0, 0, 0, 0)

#pragma unroll 1
  for (int it = 0; it < 16; ++it) {
    int kt2 = 2 * it + 2; if (kt2 > 31) kt2 = 31;
    int kt3 = 2 * it + 3; if (kt3 > 31) kt3 = 31;
    const char* sA1 = pA + (2 * it + 1) * 128;
    const char* sA2 = pA + kt2 * 128;
    const char* sA3 = pA + kt3 * 128;
    const char* sB2 = pB + kt2 * 128;
    const char* sB3 = pB + kt3 * 128;

    // ph0: consume (fa0,fb0)=t.kh0.mh0; issue fa1 <- t.kh0.mh1
    BARR;
    STAGE(sA1 + 64, 49152);          // t+1.A.kh1 (dead since prev ph7 consume)
    ISS_A(fa1, 0, 0, 1)
    LGKM4; SCHED0; MFMA16(fa0, fb0, 0)
    // ph1: consume (fa1,fb0); issue (fb1,fa0) <- t.kh1
    BARR;
    STAGE(sB2, 65536);               // t+2.B.kh0
    ISS_B(fb1, 0, 1) ISS_A(fa0, 0, 1, 0)
    LGKM8; SCHED0; MFMA16(fa1, fb0, 1)
    VM6;
    // ph2: consume (fa0,fb1); issue fa1 <- t.kh1.mh1
    BARR;
    STAGE(sA2, 0);                   // t+2.A.kh0
    ISS_A(fa1, 0, 1, 1)
    LGKM4; SCHED0; MFMA16(fa0, fb1, 0)
    // ph3: consume (fa1,fb1); issue (fb0,fa0) <- t+1.kh0
    BARR;
    STAGE(sB2 + 64, 81920);          // t+2.B.kh1
    ISS_B(fb0, 1, 0) ISS_A(fa0, 1, 0, 0)
    LGKM8; SCHED0; MFMA16(fa1, fb1, 1)
    VM6;
    // ph4: consume (fa0,fb0); issue fa1 <- t+1.kh0.mh1
    BARR;
    STAGE(sA2 + 64, 16384);          // t+2.A.kh1
    ISS_A(fa1, 1, 0, 1)
    LGKM4; SCHED0; MFMA16(fa0, fb0, 0)
    // ph5: consume (fa1,fb0); issue (fb1,fa0) <- t+1.kh1
    BARR;
    STAGE(sB3, 98304);               // t+3.B.kh0
    ISS_B(fb1, 1, 1) ISS_A(fa0, 1, 1, 0)
    LGKM8; SCHED0; MFMA16(fa1, fb0, 1)
    VM6;
    // ph6: consume (fa0,fb1); issue fa1 <- t+1.kh1.mh1
    BARR;
    STAGE(sA3, 32768);               // t+3.A.kh0
    ISS_A(fa1, 1, 1, 1)
    LGKM4; SCHED0; MFMA16(fa0, fb1, 0)
    // ph7: consume (fa1,fb1); issue (fb0,fa0) <- next-iter t.kh0
    BARR;
    STAGE(sB3 + 64, 114688);         // t+3.B.kh1
    ISS_B(fb0, 0, 0) ISS_A(fa0, 0, 0, 0)
    LGKM8; SCHED0; MFMA16(fa1, fb1, 1)
    VM6;
  }

  // ---- fused LSTM epilogue (drain, then reuse LDS; wave-private) ----
  VM0;
  __syncthreads();
  float* ew = (float*)smem_ + w * 1088;     // 16 x 68 floats per wave
  const float4 bias4 = *(const float4*)(bias + n0 + wc * 64 + 4 * la);
  const int hg = ((n0 + wc * 64) >> 2) + la;
  const int brow0 = m0 + wr * 128;

  // Prefetch all 32 c_prev values (static unrolled indices -> registers, not scratch);
  // the 8x(16 LDS writes + 4 b128 reads) transpose below hides their L3/HBM latency.
  float cpv[8][4];
#pragma unroll
  for (int mi = 0; mi < 8; ++mi)
#pragma unroll
    for (int p = 0; p < 4; ++p)
      cpv[mi][p] = c_prev[(uint32_t)(brow0 + mi * 16 + p * 4 + kg) * HDIM + (uint32_t)hg];

#pragma unroll
  for (int mi = 0; mi < 8; ++mi) {
#pragma unroll
    for (int ni = 0; ni < 4; ++ni)
#pragma unroll
      for (int r = 0; r < 4; ++r)
        ew[(4 * kg + r) * 68 + ni * 16 + la] = acc[mi][ni][r];
#pragma unroll
    for (int p = 0; p < 4; ++p) {
      const int row = p * 4 + kg;
      float4 g4 = *(const float4*)(ew + row * 68 + 4 * la);   // z,i,f,o for one (b,h)
      const int b = brow0 + mi * 16 + row;
      const uint32_t oidx = (uint32_t)b * HDIM + (uint32_t)hg;
      const float cp = cpv[mi][p];
      const float zg = tanh_f(g4.x + bias4.x);
      const float ig = sigmoid_f(g4.y + bias4.y);
      const float fg = sigmoid_f(g4.z + bias4.z);
      const float og = sigmoid_f(g4.w + bias4.w);
      const float cn = fg * cp + ig * zg;
      out_h[oidx] = og * tanh_f(cn);
      out_c[oidx] = cn;
    }
  }
}

extern "C" void kernel_launch(void* const* d_in, const int* in_sizes, int n_in,
                              void* d_out, int out_size, void* d_ws, size_t ws_size,
                              hipStream_t stream) {
  const float* x  = (const float*)d_in[0];
  const float* hp = (const float*)d_in[1];
  const float* cp = (const float*)d_in[2];
  const float* Wx = (const float*)d_in[3];
  const float* bx = (const float*)d_in[4];
  const float* Rh = (const float*)d_in[5];
  const float* bh = (const float*)d_in[6];

  unsigned short* XH = (unsigned short*)d_ws;                 // 64 MB
  unsigned short* Wp = XH + (size_t)BATCH * KDIM;             // 16 MB
  float* bias = (float*)(Wp + (size_t)NDIM * KDIM);           // 16 KB
  float* out_h = (float*)d_out;
  float* out_c = out_h + (size_t)BATCH * HDIM;

  pack_all<<<3072, 256, 0, stream>>>(x, hp, Wx, Rh, bx, bh, XH, Wp, bias);
  lstm_gemm<<<1024, 512, 0, stream>>>(XH, Wp, bias, cp, out_h, out_c);
}